// Round 2
// baseline (180.802 us; speedup 1.0000x reference)
//
#include <hip/hip_runtime.h>
#include <hip/hip_cooperative_groups.h>
#include <cstdint>

namespace cg = cooperative_groups;

#define BSZ 512   // batch
#define CSZ 256   // concepts

// ---------------- block reduction helpers (256 threads) ----------------
__device__ __forceinline__ float block_reduce_max256(float v, float* scratch) {
    int tid = threadIdx.x;
    scratch[tid] = v;
    __syncthreads();
    for (int s = 128; s > 0; s >>= 1) {
        if (tid < s) scratch[tid] = fmaxf(scratch[tid], scratch[tid + s]);
        __syncthreads();
    }
    float r = scratch[0];
    __syncthreads();
    return r;
}

__device__ __forceinline__ float block_reduce_sum256(float v, float* scratch) {
    int tid = threadIdx.x;
    scratch[tid] = v;
    __syncthreads();
    for (int s = 128; s > 0; s >>= 1) {
        if (tid < s) scratch[tid] += scratch[tid + s];
        __syncthreads();
    }
    float r = scratch[0];
    __syncthreads();
    return r;
}

// ws layout (bytes from d_ws base):
//   packed : u64[BSZ*4]      @ 0       (16 KB)
//   pc     : f32[2*BSZ]      @ 16384   (clip partials: [0,512) img, [512,1024) txt)
//   pb     : f32[BSZ]        @ 20480   (bce sum per row)
//   pm     : f32[BSZ]        @ 22528   (mask count per row)
//   pk     : f32[BSZ]        @ 24576   (kl partial per row)
__global__ void fused_kernel(const float* __restrict__ img,
                             const float* __restrict__ txt,
                             const float* __restrict__ clog,
                             const float* __restrict__ csim,
                             const int* __restrict__ mc,
                             float* __restrict__ out,
                             char* __restrict__ ws) {
    __shared__ unsigned long long wb[BSZ * 4];  // 16 KB
    __shared__ float sdat[BSZ];
    __shared__ float cdat[BSZ];
    __shared__ float scratch[256];

    unsigned long long* packed = (unsigned long long*)(ws);
    float* pc = (float*)(ws + 16384);
    float* pb = (float*)(ws + 20480);
    float* pm = (float*)(ws + 22528);
    float* pk = (float*)(ws + 24576);

    cg::grid_group grid = cg::this_grid();
    int b = blockIdx.x, tid = threadIdx.x;

    // ---------------- Phase 1: clip rows + concept BCE + bit-pack ----------------
    {
        // clip image row b
        const float* r = img + (size_t)b * BSZ;
        float x0 = r[tid], x1 = r[tid + 256];
        float mx = block_reduce_max256(fmaxf(x0, x1), scratch);
        float se = block_reduce_sum256(expf(x0 - mx) + expf(x1 - mx), scratch);
        if (tid == 0) pc[b] = mx + logf(se) - r[b];

        // clip text row b
        r = txt + (size_t)b * BSZ;
        x0 = r[tid]; x1 = r[tid + 256];
        mx = block_reduce_max256(fmaxf(x0, x1), scratch);
        se = block_reduce_sum256(expf(x0 - mx) + expf(x1 - mx), scratch);
        if (tid == 0) pc[BSZ + b] = mx + logf(se) - r[b];

        // concept BCE row b + pack
        int m = mc[b * CSZ + tid];
        float x = clog[b * CSZ + tid];
        float maskf = (m != -1) ? 1.0f : 0.0f;
        float t = (m == 1) ? 1.0f : 0.0f;
        float loss = (fmaxf(x, 0.0f) + log1pf(expf(-fabsf(x))) - x * t) * maskf;
        float ls = block_reduce_sum256(loss, scratch);
        float ms = block_reduce_sum256(maskf, scratch);
        if (tid == 0) { pb[b] = ls; pm[b] = ms; }
        unsigned long long bal = __ballot(m == 1);
        if ((tid & 63) == 0) packed[b * 4 + (tid >> 6)] = bal;
    }

    grid.sync();

    // ---------------- Phase 2: Jaccard sims + softmax targets + KL ----------------
    {
        for (int k = tid; k < BSZ * 4; k += 256) wb[k] = packed[k];
        __syncthreads();
        unsigned long long a0 = wb[b * 4 + 0], a1 = wb[b * 4 + 1];
        unsigned long long a2 = wb[b * 4 + 2], a3 = wb[b * 4 + 3];
        for (int j = tid; j < BSZ; j += 256) {
            unsigned long long b0 = wb[j * 4 + 0], b1 = wb[j * 4 + 1];
            unsigned long long b2 = wb[j * 4 + 2], b3 = wb[j * 4 + 3];
            int inter = __popcll(a0 & b0) + __popcll(a1 & b1) + __popcll(a2 & b2) + __popcll(a3 & b3);
            int uni   = __popcll(a0 | b0) + __popcll(a1 | b1) + __popcll(a2 | b2) + __popcll(a3 | b3);
            float sim = (uni > 0) ? ((float)inter / (float)uni) : 0.0f;
            sdat[j] = sim * (1.0f / 0.07f);
            cdat[j] = csim[(size_t)b * BSZ + j];
        }
        __syncthreads();
        float s0 = sdat[tid], s1 = sdat[tid + 256];
        float c0 = cdat[tid], c1 = cdat[tid + 256];
        float mx_s = block_reduce_max256(fmaxf(s0, s1), scratch);
        float Zs = block_reduce_sum256(expf(s0 - mx_s) + expf(s1 - mx_s), scratch);
        float lse_s = mx_s + logf(Zs);
        float mx_c = block_reduce_max256(fmaxf(c0, c1), scratch);
        float Zc = block_reduce_sum256(expf(c0 - mx_c) + expf(c1 - mx_c), scratch);
        float lse_c = mx_c + logf(Zc);
        float t0 = expf(s0 - lse_s), t1 = expf(s1 - lse_s);
        float kl0 = t0 * ((s0 - lse_s) - (c0 - lse_c));
        float kl1 = t1 * ((s1 - lse_s) - (c1 - lse_c));
        float kl = block_reduce_sum256(kl0 + kl1, scratch);
        if (tid == 0) pk[b] = kl;
    }

    grid.sync();

    // ---------------- Phase 3: final reduce (block 0 only) ----------------
    if (b == 0) {
        float s_clip = 0.0f, s_b = 0.0f, s_m = 0.0f, s_k = 0.0f;
        for (int k = tid; k < 2 * BSZ; k += 256) s_clip += pc[k];
        for (int k = tid; k < BSZ; k += 256) { s_b += pb[k]; s_m += pm[k]; s_k += pk[k]; }
        s_clip = block_reduce_sum256(s_clip, scratch);
        s_b    = block_reduce_sum256(s_b, scratch);
        s_m    = block_reduce_sum256(s_m, scratch);
        s_k    = block_reduce_sum256(s_k, scratch);
        if (tid == 0) {
            float clip_loss = s_clip / (2.0f * BSZ);
            float concept_loss = s_b / (s_m + 1e-8f);
            float klm = s_k / (float)BSZ;
            out[0] = clip_loss + 0.5f * concept_loss + 0.3f * klm;
        }
    }
}

extern "C" void kernel_launch(void* const* d_in, const int* in_sizes, int n_in,
                              void* d_out, int out_size, void* d_ws, size_t ws_size,
                              hipStream_t stream) {
    const float* logits_img = (const float*)d_in[0];   // [512,512]
    const float* logits_txt = (const float*)d_in[1];   // [512,512]
    const float* clog       = (const float*)d_in[2];   // [512,256]
    const float* csim       = (const float*)d_in[3];   // [512,512]
    const int*   mc         = (const int*)d_in[4];     // [512,256]
    float* out = (float*)d_out;
    char* ws = (char*)d_ws;

    void* args[] = {(void*)&logits_img, (void*)&logits_txt, (void*)&clog,
                    (void*)&csim, (void*)&mc, (void*)&out, (void*)&ws};
    hipLaunchCooperativeKernel((const void*)fused_kernel, dim3(BSZ), dim3(256),
                               args, 0, stream);
}

// Round 3
// 89.119 us; speedup vs baseline: 2.0288x; 2.0288x over previous
//
#include <hip/hip_runtime.h>
#include <cstdint>

#define BSZ 512   // batch
#define CSZ 256   // concepts

// ---------------- block reduction helpers (256 threads) ----------------
__device__ __forceinline__ float block_reduce_max256(float v, float* scratch) {
    int tid = threadIdx.x;
    scratch[tid] = v;
    __syncthreads();
    for (int s = 128; s > 0; s >>= 1) {
        if (tid < s) scratch[tid] = fmaxf(scratch[tid], scratch[tid + s]);
        __syncthreads();
    }
    float r = scratch[0];
    __syncthreads();
    return r;
}

__device__ __forceinline__ float block_reduce_sum256(float v, float* scratch) {
    int tid = threadIdx.x;
    scratch[tid] = v;
    __syncthreads();
    for (int s = 128; s > 0; s >>= 1) {
        if (tid < s) scratch[tid] += scratch[tid + s];
        __syncthreads();
    }
    float r = scratch[0];
    __syncthreads();
    return r;
}

// ws layout (bytes from d_ws base):
//   packed : u64[BSZ*4]      @ 0       (16 KB)
//   pc     : f32[2*BSZ]      @ 16384   (clip partials: [0,512) img, [512,1024) txt)
//   pb     : f32[BSZ]        @ 20480   (bce sum per row)
//   pm     : f32[BSZ]        @ 22528   (mask count per row)
//   acc    : f32[1]          @ 24576   (kl accumulator)
//   done   : u32[1]          @ 24580   (ticket counter)

// Kernel A: clip rows (img+txt) + concept BCE + bit-pack + zero accumulators.
__global__ void prep_kernel(const float* __restrict__ img,
                            const float* __restrict__ txt,
                            const float* __restrict__ clog,
                            const int* __restrict__ mc,
                            char* __restrict__ ws) {
    __shared__ float scratch[256];
    unsigned long long* packed = (unsigned long long*)(ws);
    float* pc = (float*)(ws + 16384);
    float* pb = (float*)(ws + 20480);
    float* pm = (float*)(ws + 22528);

    int b = blockIdx.x, tid = threadIdx.x;

    if (b == 0 && tid == 0) {
        *(float*)(ws + 24576) = 0.0f;           // kl accumulator
        *(unsigned int*)(ws + 24580) = 0u;      // ticket counter
    }

    // clip image row b
    const float* r = img + (size_t)b * BSZ;
    float x0 = r[tid], x1 = r[tid + 256];
    float mx = block_reduce_max256(fmaxf(x0, x1), scratch);
    float se = block_reduce_sum256(expf(x0 - mx) + expf(x1 - mx), scratch);
    if (tid == 0) pc[b] = mx + logf(se) - r[b];

    // clip text row b
    r = txt + (size_t)b * BSZ;
    x0 = r[tid]; x1 = r[tid + 256];
    mx = block_reduce_max256(fmaxf(x0, x1), scratch);
    se = block_reduce_sum256(expf(x0 - mx) + expf(x1 - mx), scratch);
    if (tid == 0) pc[BSZ + b] = mx + logf(se) - r[b];

    // concept BCE row b + bit-pack (w = 1 iff mc == 1)
    int m = mc[b * CSZ + tid];
    float x = clog[b * CSZ + tid];
    float maskf = (m != -1) ? 1.0f : 0.0f;
    float t = (m == 1) ? 1.0f : 0.0f;
    float loss = (fmaxf(x, 0.0f) + log1pf(expf(-fabsf(x))) - x * t) * maskf;
    float ls = block_reduce_sum256(loss, scratch);
    float ms = block_reduce_sum256(maskf, scratch);
    if (tid == 0) { pb[b] = ls; pm[b] = ms; }
    unsigned long long bal = __ballot(m == 1);
    if ((tid & 63) == 0) packed[b * 4 + (tid >> 6)] = bal;
}

// Kernel B: Jaccard + softmax targets + KL per row; last block finalizes.
__global__ void sim_final_kernel(const float* __restrict__ csim,
                                 char* __restrict__ ws,
                                 float* __restrict__ out) {
    __shared__ unsigned long long wb[BSZ * 4];  // 16 KB
    __shared__ float sdat[BSZ];
    __shared__ float cdat[BSZ];
    __shared__ float scratch[256];
    __shared__ int islast;

    unsigned long long* packed = (unsigned long long*)(ws);
    float* pc = (float*)(ws + 16384);
    float* pb = (float*)(ws + 20480);
    float* pm = (float*)(ws + 22528);
    float* acc = (float*)(ws + 24576);
    unsigned int* done = (unsigned int*)(ws + 24580);

    int b = blockIdx.x, tid = threadIdx.x;

    for (int k = tid; k < BSZ * 4; k += 256) wb[k] = packed[k];
    __syncthreads();
    unsigned long long a0 = wb[b * 4 + 0], a1 = wb[b * 4 + 1];
    unsigned long long a2 = wb[b * 4 + 2], a3 = wb[b * 4 + 3];
    for (int j = tid; j < BSZ; j += 256) {
        unsigned long long b0 = wb[j * 4 + 0], b1 = wb[j * 4 + 1];
        unsigned long long b2 = wb[j * 4 + 2], b3 = wb[j * 4 + 3];
        int inter = __popcll(a0 & b0) + __popcll(a1 & b1) + __popcll(a2 & b2) + __popcll(a3 & b3);
        int uni   = __popcll(a0 | b0) + __popcll(a1 | b1) + __popcll(a2 | b2) + __popcll(a3 | b3);
        float sim = (uni > 0) ? ((float)inter / (float)uni) : 0.0f;
        sdat[j] = sim * (1.0f / 0.07f);
        cdat[j] = csim[(size_t)b * BSZ + j];
    }
    __syncthreads();
    float s0 = sdat[tid], s1 = sdat[tid + 256];
    float c0 = cdat[tid], c1 = cdat[tid + 256];
    float mx_s = block_reduce_max256(fmaxf(s0, s1), scratch);
    float Zs = block_reduce_sum256(expf(s0 - mx_s) + expf(s1 - mx_s), scratch);
    float lse_s = mx_s + logf(Zs);
    float mx_c = block_reduce_max256(fmaxf(c0, c1), scratch);
    float Zc = block_reduce_sum256(expf(c0 - mx_c) + expf(c1 - mx_c), scratch);
    float lse_c = mx_c + logf(Zc);
    float t0 = expf(s0 - lse_s), t1 = expf(s1 - lse_s);
    float kl0 = t0 * ((s0 - lse_s) - (c0 - lse_c));
    float kl1 = t1 * ((s1 - lse_s) - (c1 - lse_c));
    float kl = block_reduce_sum256(kl0 + kl1, scratch);

    if (tid == 0) {
        atomicAdd(acc, kl);               // device-scope
        __threadfence();
        unsigned int ticket = atomicAdd(done, 1u);
        islast = (ticket == BSZ - 1) ? 1 : 0;
    }
    __syncthreads();

    if (islast) {
        // Final reduction: pc/pb/pm were written by prep_kernel (visible via
        // kernel boundary); kl total is in acc (all adds fenced before ticket).
        float s_clip = 0.0f, s_b = 0.0f, s_m = 0.0f;
        for (int k = tid; k < 2 * BSZ; k += 256) s_clip += pc[k];
        for (int k = tid; k < BSZ; k += 256) { s_b += pb[k]; s_m += pm[k]; }
        s_clip = block_reduce_sum256(s_clip, scratch);
        s_b    = block_reduce_sum256(s_b, scratch);
        s_m    = block_reduce_sum256(s_m, scratch);
        if (tid == 0) {
            float klsum = atomicAdd(acc, 0.0f);   // coherent read
            float clip_loss = s_clip / (2.0f * BSZ);
            float concept_loss = s_b / (s_m + 1e-8f);
            float klm = klsum / (float)BSZ;
            out[0] = clip_loss + 0.5f * concept_loss + 0.3f * klm;
        }
    }
}

extern "C" void kernel_launch(void* const* d_in, const int* in_sizes, int n_in,
                              void* d_out, int out_size, void* d_ws, size_t ws_size,
                              hipStream_t stream) {
    const float* logits_img = (const float*)d_in[0];   // [512,512]
    const float* logits_txt = (const float*)d_in[1];   // [512,512]
    const float* clog       = (const float*)d_in[2];   // [512,256]
    const float* csim       = (const float*)d_in[3];   // [512,512]
    const int*   mc         = (const int*)d_in[4];     // [512,256]
    float* out = (float*)d_out;
    char* ws = (char*)d_ws;

    prep_kernel<<<BSZ, 256, 0, stream>>>(logits_img, logits_txt, clog, mc, ws);
    sim_final_kernel<<<BSZ, 256, 0, stream>>>(csim, ws, out);
}